// Round 10
// baseline (425.088 us; speedup 1.0000x reference)
//
#include <hip/hip_runtime.h>
#include <hip/hip_bf16.h>

#define NN 50000
#define NE 800000
#define DD 128
#define SLAB 64             // fixed esrc slab per node (max padded degree; P(deg>=64)~1e-22)
#define GEMM_BLKS 471       // 157 x 3 manifolds

typedef unsigned int u32;
typedef __attribute__((ext_vector_type(8))) short short8;   // 8 bf16 = 4 VGPRs
typedef __attribute__((ext_vector_type(4))) float f32x4;
typedef __attribute__((ext_vector_type(2))) float f32x2;
typedef __attribute__((ext_vector_type(4))) u32 u32x4;

__device__ __forceinline__ u32 f2bf2(float a, float b){
  union { __hip_bfloat162 h; u32 u; } cv;
  cv.h = __float22bfloat162_rn(make_float2(a, b));   // v_cvt_pk_bf16_f32 on gfx950
  return cv.u;
}
__device__ __forceinline__ f32x2 up2(u32 v){
  f32x2 r;
  r.x = __uint_as_float(v << 16);
  r.y = __uint_as_float(v & 0xffff0000u);
  return r;
}

// pack one frag-lane slot of a 128x128 fp32 mat into 4 u32 (8 bf16).
// slot idx: frag = idx>>6 (ct=frag>>2, ks=frag&3), lane = idx&63 (rr=lane&15, quad=lane>>4)
__device__ __forceinline__ u32x4 pack_slot(const float* Wm, int idx){
  int frag = idx >> 6, ln = idx & 63;
  int ct = frag >> 2, ks = frag & 3, rr = ln & 15, qd = ln >> 4;
  const float* p = Wm + (ct*16 + rr)*128 + ks*32 + qd*8;
  float4 f0 = *(const float4*)p;
  float4 f1 = *(const float4*)(p + 4);
  u32x4 q;
  q.x = f2bf2(f0.x, f0.y); q.y = f2bf2(f0.z, f0.w);
  q.z = f2bf2(f1.x, f1.y); q.w = f2bf2(f1.z, f1.w);
  return q;
}

// -------- k_main: full layer-0 GEMM (471 blocks) + side work (3129 blocks) ------
// gemm blocks self-pack their layer-0 W (fp32, L2-hot) into LDS, then walk their
// 5 groups with a 2-group straight-line unroll (next group's 8 A-loads stay in
// flight under the current group's norm/pack/MFMA chain -> latency hidden).
// side blocks 0-2: pack layer-1 W mats into global wf1 (read by k_fused).
// side block 3:   zero rows 0 of h0/h1 (gather target of pad slots).
// side blocks 4+: single-pass CSR build -- p = atomicAdd(cnt[dst]); slab write.
// H: row (node+1) at H+(node+1)*192 dw, manifold m at +m*64 dw.
// esrc entries: pre-scaled dword offsets (src+1)*192.
struct MainArgs {
  const float* A[3];
  const float* Bias[3];
  const float* W[3];      // layer-0 fp32 weights
  const float* W1[3];     // layer-1 fp32 weights
  u32* wf1;               // layer-1 frag-packed out (3 x 2048 x 16 B)
  u32* H;                 // h0
  u32* H1;                // h1 (row-0 zeroing only)
  const float* curv;
  const int* src;
  const int* dst;
  int* cnt;
  int* esrc;
};

__global__ __launch_bounds__(256,3) void k_main(MainArgs ma){
  const int bx = blockIdx.x;
  const int t = threadIdx.x;
  if (bx >= GEMM_BLKS){     // ---- side-work blocks (hide under the gemm) ----
    int sb = bx - GEMM_BLKS;
    if (sb < 3){            // pack layer-1 weight mat sb -> global
      const float* Wm = ma.W1[sb];
      #pragma unroll
      for (int it = 0; it < 8; ++it){
        int idx = it*256 + t;
        u32x4 q = pack_slot(Wm, idx);
        *(u32x4*)(ma.wf1 + (size_t)(sb*2048 + idx)*4) = q;
      }
    } else if (sb == 3){    // zero rows (pads gather these)
      if (t < 192){ ma.H[t] = 0; ma.H1[t] = 0; }
    } else {
      int i = (sb - 4)*256 + t;
      if (i < NE){
        int d = ma.dst[i];
        int p = atomicAdd(&ma.cnt[d], 1);
        if (p < SLAB) ma.esrc[d*SLAB + p] = (ma.src[i] + 1) * 192;
      }
    }
    return;
  }
  const int m  = bx / 157;
  const int gx = bx % 157;
  const float* __restrict__ A    = ma.A[m];
  const float* __restrict__ Bias = ma.Bias[m];
  u32* __restrict__ H = ma.H;
  const int lane = t & 63;
  const int rr = lane & 15, quad = lane >> 4;

  __shared__ u32 Wlds[8192];        // 32 frags x 64 lanes x 16 B, conflict-free b128
  {
    const float* Wm = ma.W[m];      // self-pack fp32 -> bf16 frags (L2-hot)
    #pragma unroll
    for (int it = 0; it < 8; ++it){
      int idx = it*256 + t;
      u32x4 q = pack_slot(Wm, idx);
      *(u32x4*)&Wlds[idx*4] = q;
    }
  }
  __syncthreads();                  // the only barrier in the kernel

  float sc = 1.f;
  if (m == 1) sc = sqrtf(*ma.curv);

  auto loadg = [&](int g, float4* c){
    const float* ap = A + (size_t)(g*16 + rr)*DD + quad*8;
    #pragma unroll
    for (int ks = 0; ks < 4; ++ks){
      c[2*ks]   = *(const float4*)(ap + ks*32);
      c[2*ks+1] = *(const float4*)(ap + ks*32 + 4);
    }
  };
  auto body = [&](int g, float4* c){
    if (m != 0){
      float p = 0.f;
      #pragma unroll
      for (int i = 0; i < 8; ++i)
        p += c[i].x*c[i].x + c[i].y*c[i].y + c[i].z*c[i].z + c[i].w*c[i].w;
      p += __shfl_xor(p, 16, 64);
      p += __shfl_xor(p, 32, 64);
      float nrm = sqrtf(p);
      float sca;
      if (m == 1){    // log-map at origin: (2/sc)*artanh(sc*|y|)/|y|
        float x = sc * nrm;
        sca = (nrm > 1e-30f) ? (logf((1.f + x)/(1.f - x)) / (sc * nrm)) : 2.f;
      } else {        // l2norm
        sca = 1.f / fmaxf(nrm, 1e-12f);
      }
      #pragma unroll
      for (int i = 0; i < 8; ++i){ c[i].x*=sca; c[i].y*=sca; c[i].z*=sca; c[i].w*=sca; }
    }
    f32x4 acc[8];
    #pragma unroll
    for (int ct = 0; ct < 8; ++ct){ f32x4 z = {0.f,0.f,0.f,0.f}; acc[ct] = z; }
    #pragma unroll
    for (int ks = 0; ks < 4; ++ks){
      u32x4 bq;
      bq.x = f2bf2(c[2*ks].x,   c[2*ks].y);
      bq.y = f2bf2(c[2*ks].z,   c[2*ks].w);
      bq.z = f2bf2(c[2*ks+1].x, c[2*ks+1].y);
      bq.w = f2bf2(c[2*ks+1].z, c[2*ks+1].w);
      short8 bf = __builtin_bit_cast(short8, bq);
      #pragma unroll
      for (int ct = 0; ct < 8; ++ct){
        short8 wf = *(const short8*)&Wlds[((ct*4 + ks)*64 + lane)*4];
        acc[ct] = __builtin_amdgcn_mfma_f32_16x16x32_bf16(wf, bf, acc[ct], 0, 0, 0);
      }
    }
    #pragma unroll
    for (int ct = 0; ct < 8; ++ct){
      float4 bv = *(const float4*)(Bias + ct*16 + quad*4);
      acc[ct].x += bv.x; acc[ct].y += bv.y; acc[ct].z += bv.z; acc[ct].w += bv.w;
    }
    if (m == 2){
      float p = 0.f;
      #pragma unroll
      for (int ct = 0; ct < 8; ++ct)
        p += acc[ct].x*acc[ct].x + acc[ct].y*acc[ct].y + acc[ct].z*acc[ct].z + acc[ct].w*acc[ct].w;
      p += __shfl_xor(p, 16, 64);
      p += __shfl_xor(p, 32, 64);
      float inv = 1.f / fmaxf(sqrtf(p), 1e-12f);
      #pragma unroll
      for (int ct = 0; ct < 8; ++ct){ acc[ct].x*=inv; acc[ct].y*=inv; acc[ct].z*=inv; acc[ct].w*=inv; }
    }
    u32* hp = H + (size_t)(g*16 + rr + 1)*192 + m*64 + quad*2;
    #pragma unroll
    for (int ct = 0; ct < 8; ++ct){
      uint2 pk;
      pk.x = f2bf2(acc[ct].x, acc[ct].y);
      pk.y = f2bf2(acc[ct].z, acc[ct].w);
      *(uint2*)(hp + ct*8) = pk;
    }
  };

  const int nw = 157*4;
  for (int g = gx*4 + (t >> 6); g < 3125; g += 2*nw){
    const int g2 = g + nw;                 // wave-uniform -> uniform branch
    float4 c0[8], c1[8];
    loadg(g, c0);
    const bool has2 = (g2 < 3125);
    if (has2) loadg(g2, c1);               // 8 more loads in flight under body(g)
    body(g, c0);
    if (has2) body(g2, c1);
  }
}

// ------------- fused agg(layer0) + gemm(layer1): H0 --gather--> H1 ---------------
// Identities: log_map(0, exp_map(0, v)) = v and l2norm(l2norm(x)) = l2norm(x), so
// aggregated means feed layer-1's matmul directly: m0 leakyrelu, m1 nothing,
// m2 one l2norm. Block = 4 waves = 16 nodes (NN = 3125*16). Phase 1: each wave
// aggregates 4 nodes; fp32 aggregates to LDS. Phase 2: waves 0-2 run the
// 16x128x128 GEMM for manifold w (B-frags from LDS, W-frags from L2), write H1.
struct FusedArgs {
  const u32* H0;
  u32* H1;
  const int* cnt;
  const int* esrc;
  const u32* Wf;          // layer-1 frag-packed weights (3 mats at +m*2048*4)
  const float* Bias[3];   // layer-1 biases
};

#define NSTR 388            // node stride in dwords (384 + 4 pad -> 2-way banks max)

__global__ __launch_bounds__(256,4) void k_fused(FusedArgs fa){
  const int t = threadIdx.x;
  const int w = t >> 6;
  const int lane = t & 63;
  const int half = lane >> 5, hl = lane & 31;
  const int rr = lane & 15, quad = lane >> 4;
  const int nbase = blockIdx.x * 16;

  __shared__ float S[16*NSTR];     // [node][m0:128 | m1:128 | m2:128 | pad4]

  // ---- phase 1: aggregate 4 nodes per wave ----
  for (int i = 0; i < 4; ++i){
    const int nb = w*4 + i;
    const int node = nbase + nb;
    const int deg = fa.cnt[node];
    const int e0 = node*SLAB;
    const int e1 = e0 + ((deg + 1) & ~1);
    const int* __restrict__ esrc = fa.esrc;
    const u32* __restrict__ Hf = fa.H0 + hl*2;

    f32x2 z2 = {0.f, 0.f};
    f32x2 a0[2] = {z2, z2};
    f32x2 a1[2] = {z2, z2};
    f32x2 a2[2] = {z2, z2};

    for (int base = e0; base < e1; base += 64){
      int nn = e1 - base; if (nn > 64) nn = 64;     // always even
      int sv = esrc[base + lane];                    // in-slab, zero-padded
      int np = nn >> 1;
      int p = 0;
      for (; p + 4 <= np; p += 4){
        uint2 q[4][3];
        #pragma unroll
        for (int u = 0; u < 4; ++u){
          int soff = __shfl(sv, 2*(p + u) + half, 64);
          const u32* hp = Hf + soff;
          q[u][0] = *(const uint2*)hp;
          q[u][1] = *(const uint2*)(hp + 64);
          q[u][2] = *(const uint2*)(hp + 128);
        }
        #pragma unroll
        for (int u = 0; u < 4; ++u){
          a0[0] += up2(q[u][0].x); a0[1] += up2(q[u][0].y);
          a1[0] += up2(q[u][1].x); a1[1] += up2(q[u][1].y);
          a2[0] += up2(q[u][2].x); a2[1] += up2(q[u][2].y);
        }
      }
      for (; p < np; ++p){
        int soff = __shfl(sv, 2*p + half, 64);
        const u32* hp = Hf + soff;
        uint2 q0 = *(const uint2*)hp;
        uint2 q1 = *(const uint2*)(hp + 64);
        uint2 q2 = *(const uint2*)(hp + 128);
        a0[0] += up2(q0.x); a0[1] += up2(q0.y);
        a1[0] += up2(q1.x); a1[1] += up2(q1.y);
        a2[0] += up2(q2.x); a2[1] += up2(q2.y);
      }
    }

    #pragma unroll
    for (int j = 0; j < 2; ++j){
      a0[j].x += __shfl_xor(a0[j].x, 32, 64); a0[j].y += __shfl_xor(a0[j].y, 32, 64);
      a1[j].x += __shfl_xor(a1[j].x, 32, 64); a1[j].y += __shfl_xor(a1[j].y, 32, 64);
      a2[j].x += __shfl_xor(a2[j].x, 32, 64); a2[j].y += __shfl_xor(a2[j].y, 32, 64);
    }
    float inv = 1.f / (float)max(deg, 1);
    #pragma unroll
    for (int j = 0; j < 2; ++j){ a0[j] *= inv; a1[j] *= inv; a2[j] *= inv; }

    // m2: single l2norm (idempotent; layer-1 pre-transform folded)
    float p2 = a2[0].x*a2[0].x + a2[0].y*a2[0].y + a2[1].x*a2[1].x + a2[1].y*a2[1].y;
    #pragma unroll
    for (int off = 1; off < 32; off <<= 1) p2 += __shfl_xor(p2, off, 64);
    float s2 = 1.f / fmaxf(sqrtf(p2), 1e-12f);

    float* sp = &S[nb*NSTR];
    if (half == 0){
      f32x4 v0 = { a0[0].x > 0.f ? a0[0].x : 0.2f*a0[0].x,
                   a0[0].y > 0.f ? a0[0].y : 0.2f*a0[0].y,
                   a0[1].x > 0.f ? a0[1].x : 0.2f*a0[1].x,
                   a0[1].y > 0.f ? a0[1].y : 0.2f*a0[1].y };
      *(f32x4*)(sp + hl*4) = v0;
      f32x4 v1 = { a1[0].x, a1[0].y, a1[1].x, a1[1].y };   // identity (log∘exp)
      *(f32x4*)(sp + 128 + hl*4) = v1;
    } else {
      f32x4 v2 = { a2[0].x*s2, a2[0].y*s2, a2[1].x*s2, a2[1].y*s2 };
      *(f32x4*)(sp + 256 + hl*4) = v2;
    }
  }
  __syncthreads();

  // ---- phase 2: wave w < 3 computes manifold w's 16x128 output tile ----
  if (w < 3){
    const int m = w;
    short8 bf[4];
    const float* sp = &S[rr*NSTR + m*128];
    #pragma unroll
    for (int ks = 0; ks < 4; ++ks){
      f32x4 lo = *(const f32x4*)(sp + ks*32 + quad*8);
      f32x4 hi = *(const f32x4*)(sp + ks*32 + quad*8 + 4);
      u32x4 bq;
      bq.x = f2bf2(lo.x, lo.y); bq.y = f2bf2(lo.z, lo.w);
      bq.z = f2bf2(hi.x, hi.y); bq.w = f2bf2(hi.z, hi.w);
      bf[ks] = __builtin_bit_cast(short8, bq);
    }
    const u32* __restrict__ wbase = fa.Wf + (size_t)m*8192;
    const float* __restrict__ Bias = fa.Bias[m];
    f32x4 acc[8];
    #pragma unroll
    for (int ct = 0; ct < 8; ++ct){ f32x4 z = {0.f,0.f,0.f,0.f}; acc[ct] = z; }
    #pragma unroll
    for (int ct = 0; ct < 8; ++ct){
      short8 wfr[4];
      #pragma unroll
      for (int ks = 0; ks < 4; ++ks)
        wfr[ks] = *(const short8*)(wbase + ((ct*4 + ks)*64 + lane)*4);
      #pragma unroll
      for (int ks = 0; ks < 4; ++ks)
        acc[ct] = __builtin_amdgcn_mfma_f32_16x16x32_bf16(wfr[ks], bf[ks], acc[ct], 0, 0, 0);
    }
    #pragma unroll
    for (int ct = 0; ct < 8; ++ct){
      float4 bv = *(const float4*)(Bias + ct*16 + quad*4);
      acc[ct].x += bv.x; acc[ct].y += bv.y; acc[ct].z += bv.z; acc[ct].w += bv.w;
    }
    if (m == 2){
      float p = 0.f;
      #pragma unroll
      for (int ct = 0; ct < 8; ++ct)
        p += acc[ct].x*acc[ct].x + acc[ct].y*acc[ct].y + acc[ct].z*acc[ct].z + acc[ct].w*acc[ct].w;
      p += __shfl_xor(p, 16, 64);
      p += __shfl_xor(p, 32, 64);
      float nv = 1.f / fmaxf(sqrtf(p), 1e-12f);
      #pragma unroll
      for (int ct = 0; ct < 8; ++ct){ acc[ct].x*=nv; acc[ct].y*=nv; acc[ct].z*=nv; acc[ct].w*=nv; }
    }
    u32* hp = fa.H1 + (size_t)(nbase + rr + 1)*192 + m*64 + quad*2;
    #pragma unroll
    for (int ct = 0; ct < 8; ++ct){
      uint2 pk;
      pk.x = f2bf2(acc[ct].x, acc[ct].y);
      pk.y = f2bf2(acc[ct].z, acc[ct].w);
      *(uint2*)(hp + ct*8) = pk;
    }
  }
}

// ------- final mean-aggregate + post-transform (layer 1) -------------------------
struct AggArgs {
  const u32* H;
  float* O;
  const int* cnt;
  const int* esrc;
  const float* curv;
};

__global__ __launch_bounds__(256) void k_agg(AggArgs aa){
  const int tid = threadIdx.x;
  const int lane = tid & 63;
  const int half = lane >> 5, hl = lane & 31;
  const int node = blockIdx.x*4 + (tid >> 6);
  if (node >= NN) return;
  const int deg = aa.cnt[node];
  const int e0 = node*SLAB;
  const int e1 = e0 + ((deg + 1) & ~1);
  const int* __restrict__ esrc = aa.esrc;
  const u32* __restrict__ Hf = aa.H + hl*2;

  f32x2 z2 = {0.f, 0.f};
  f32x2 a0[2] = {z2, z2};
  f32x2 a1[2] = {z2, z2};
  f32x2 a2[2] = {z2, z2};

  for (int base = e0; base < e1; base += 64){
    int nn = e1 - base; if (nn > 64) nn = 64;
    int sv = esrc[base + lane];                    // in-slab, zero-padded
    int np = nn >> 1;
    int p = 0;
    for (; p + 4 <= np; p += 4){
      uint2 q[4][3];
      #pragma unroll
      for (int u = 0; u < 4; ++u){
        int soff = __shfl(sv, 2*(p + u) + half, 64);
        const u32* hp = Hf + soff;
        q[u][0] = *(const uint2*)hp;
        q[u][1] = *(const uint2*)(hp + 64);
        q[u][2] = *(const uint2*)(hp + 128);
      }
      #pragma unroll
      for (int u = 0; u < 4; ++u){
        a0[0] += up2(q[u][0].x); a0[1] += up2(q[u][0].y);
        a1[0] += up2(q[u][1].x); a1[1] += up2(q[u][1].y);
        a2[0] += up2(q[u][2].x); a2[1] += up2(q[u][2].y);
      }
    }
    for (; p < np; ++p){
      int soff = __shfl(sv, 2*p + half, 64);
      const u32* hp = Hf + soff;
      uint2 q0 = *(const uint2*)hp;
      uint2 q1 = *(const uint2*)(hp + 64);
      uint2 q2 = *(const uint2*)(hp + 128);
      a0[0] += up2(q0.x); a0[1] += up2(q0.y);
      a1[0] += up2(q1.x); a1[1] += up2(q1.y);
      a2[0] += up2(q2.x); a2[1] += up2(q2.y);
    }
  }

  #pragma unroll
  for (int j = 0; j < 2; ++j){
    a0[j].x += __shfl_xor(a0[j].x, 32, 64); a0[j].y += __shfl_xor(a0[j].y, 32, 64);
    a1[j].x += __shfl_xor(a1[j].x, 32, 64); a1[j].y += __shfl_xor(a1[j].y, 32, 64);
    a2[j].x += __shfl_xor(a2[j].x, 32, 64); a2[j].y += __shfl_xor(a2[j].y, 32, 64);
  }
  float inv = 1.f / (float)max(deg, 1);
  #pragma unroll
  for (int j = 0; j < 2; ++j){ a0[j] *= inv; a1[j] *= inv; a2[j] *= inv; }

  float p1 = a1[0].x*a1[0].x + a1[0].y*a1[0].y + a1[1].x*a1[1].x + a1[1].y*a1[1].y;
  float p2 = a2[0].x*a2[0].x + a2[0].y*a2[0].y + a2[1].x*a2[1].x + a2[1].y*a2[1].y;
  #pragma unroll
  for (int off = 1; off < 32; off <<= 1){
    p1 += __shfl_xor(p1, off, 64);
    p2 += __shfl_xor(p2, off, 64);
  }
  float n1 = sqrtf(p1);
  float scv = sqrtf(*aa.curv);
  float x = scv * n1;
  float s1 = (n1 > 1e-30f) ? (tanhf(0.5f*x) / x) : 0.5f;   // exp-map at origin
  float s2 = 1.f / fmaxf(sqrtf(p2), 1e-12f);               // l2norm

  float* op = aa.O + (size_t)node*384;
  if (half == 0){
    float4 e4 = make_float4(a0[0].x > 0.f ? a0[0].x : 0.2f*a0[0].x,
                            a0[0].y > 0.f ? a0[0].y : 0.2f*a0[0].y,
                            a0[1].x > 0.f ? a0[1].x : 0.2f*a0[1].x,
                            a0[1].y > 0.f ? a0[1].y : 0.2f*a0[1].y);
    *(float4*)(op + hl*4) = e4;
    *(float4*)(op + 128 + hl*4) = make_float4(a1[0].x*s1, a1[0].y*s1, a1[1].x*s1, a1[1].y*s1);
  } else {
    *(float4*)(op + 256 + hl*4) = make_float4(a2[0].x*s2, a2[0].y*s2, a2[1].x*s2, a2[1].y*s2);
  }
}

extern "C" void kernel_launch(void* const* d_in, const int* in_sizes, int n_in,
                              void* d_out, int out_size, void* d_ws, size_t ws_size,
                              hipStream_t stream){
  (void)in_sizes; (void)n_in; (void)out_size; (void)ws_size;
  const int*   src    = (const int*)  d_in[0];
  const int*   dst    = (const int*)  d_in[1];
  const float* e_emb  = (const float*)d_in[2];
  const float* b_emb  = (const float*)d_in[3];
  const float* s_emb  = (const float*)d_in[4];
  const float* e_W    = (const float*)d_in[5];
  const float* e_b    = (const float*)d_in[6];
  const float* b_W    = (const float*)d_in[7];
  const float* b_b    = (const float*)d_in[8];
  const float* s_W    = (const float*)d_in[9];
  const float* s_b    = (const float*)d_in[10];
  const float* b_curv = (const float*)d_in[11];
  float* out = (float*)d_out;

  char* ws = (char*)d_ws;
  size_t off = 0;
  auto alloc = [&](size_t bytes) -> void* {
    void* p = (void*)(ws + off);
    off += (bytes + 255) & ~(size_t)255;
    return p;
  };
  int* cnt  = (int*)alloc((size_t)NN*4);              // \ contiguous: one memset
  int* esrc = (int*)alloc((size_t)NN*SLAB*4);         // /  covers both
  size_t zbytes = off;                                // cnt + esrc (+ padding)
  u32* h0   = (u32*)alloc((size_t)(NN+1)*192*4);      // row 0 zeroed in k_main
  u32* h1   = (u32*)alloc((size_t)(NN+1)*192*4);      // row 0 zeroed in k_main
  u32* wf1  = (u32*)alloc((size_t)3*2048*16);         // layer-1 frag-packed bf16 W

  (void)hipMemsetAsync(ws, 0, zbytes, stream);        // cnt + esrc in one shot

  // ----- layer-0 GEMM (unrolled x2) || {layer-1 W pack, zero rows, CSR build} ----
  MainArgs m;
  m.A[0]=e_emb; m.A[1]=b_emb; m.A[2]=s_emb;
  m.Bias[0]=e_b; m.Bias[1]=b_b; m.Bias[2]=s_b;
  m.W[0]=e_W;  m.W[1]=b_W;  m.W[2]=s_W;
  m.W1[0]=e_W+16384; m.W1[1]=b_W+16384; m.W1[2]=s_W+16384;
  m.wf1 = wf1; m.H = h0; m.H1 = h1; m.curv = b_curv;
  m.src = src; m.dst = dst; m.cnt = cnt; m.esrc = esrc;
  k_main<<<GEMM_BLKS + 4 + (NE+255)/256, 256, 0, stream>>>(m);

  // ----- fused: agg(layer0) + gemm(layer1): h0 -> h1 -----
  FusedArgs f;
  f.H0 = h0; f.H1 = h1; f.cnt = cnt; f.esrc = esrc;
  f.Wf = wf1;
  f.Bias[0] = e_b + DD; f.Bias[1] = b_b + DD; f.Bias[2] = s_b + DD;
  k_fused<<<NN/16, 256, 0, stream>>>(f);

  // ----- layer-1 aggregate + final transforms: h1 -> out -----
  AggArgs a;
  a.H = h1; a.O = out; a.cnt = cnt; a.esrc = esrc; a.curv = b_curv;
  k_agg<<<(NN + 3)/4, 256, 0, stream>>>(a);
}

// Round 11
// 391.834 us; speedup vs baseline: 1.0849x; 1.0849x over previous
//
#include <hip/hip_runtime.h>
#include <hip/hip_bf16.h>

#define NN 50000
#define NE 800000
#define DD 128
#define SLAB 64             // fixed esrc slab per node (max padded degree; P(deg>=64)~1e-22)
#define GEMM_BLKS 471       // 157 x 3 manifolds

typedef unsigned int u32;
typedef __attribute__((ext_vector_type(8))) short short8;   // 8 bf16 = 4 VGPRs
typedef __attribute__((ext_vector_type(4))) float f32x4;
typedef __attribute__((ext_vector_type(2))) float f32x2;
typedef __attribute__((ext_vector_type(4))) u32 u32x4;

__device__ __forceinline__ u32 f2bf2(float a, float b){
  union { __hip_bfloat162 h; u32 u; } cv;
  cv.h = __float22bfloat162_rn(make_float2(a, b));   // v_cvt_pk_bf16_f32 on gfx950
  return cv.u;
}
__device__ __forceinline__ f32x2 up2(u32 v){
  f32x2 r;
  r.x = __uint_as_float(v << 16);
  r.y = __uint_as_float(v & 0xffff0000u);
  return r;
}

// pack one frag-lane slot of a 128x128 fp32 mat into 4 u32 (8 bf16).
// slot idx: frag = idx>>6 (ct=frag>>2, ks=frag&3), lane = idx&63 (rr=lane&15, quad=lane>>4)
__device__ __forceinline__ u32x4 pack_slot(const float* Wm, int idx){
  int frag = idx >> 6, ln = idx & 63;
  int ct = frag >> 2, ks = frag & 3, rr = ln & 15, qd = ln >> 4;
  const float* p = Wm + (ct*16 + rr)*128 + ks*32 + qd*8;
  float4 f0 = *(const float4*)p;
  float4 f1 = *(const float4*)(p + 4);
  u32x4 q;
  q.x = f2bf2(f0.x, f0.y); q.y = f2bf2(f0.z, f0.w);
  q.z = f2bf2(f1.x, f1.y); q.w = f2bf2(f1.z, f1.w);
  return q;
}

// -------- k_main: full layer-0 GEMM (471 blocks) + side work (3129 blocks) ------
// gemm blocks self-pack their layer-0 W (fp32, L2-hot) into LDS; simple grid-stride
// over 3125 groups (round-9 form -- the x2 unroll spilled to scratch, reverted).
// side blocks 0-2: pack layer-1 W mats into global wf1 (read by k_fused).
// side block 3:   zero rows 0 of h0/h1 (gather target of pad slots).
// side blocks 4+: single-pass CSR build -- p = atomicAdd(cnt[dst]); slab write.
// H: row (node+1) at H+(node+1)*192 dw, manifold m at +m*64 dw.
// esrc entries: pre-scaled dword offsets (src+1)*192.
struct MainArgs {
  const float* A[3];
  const float* Bias[3];
  const float* W[3];      // layer-0 fp32 weights
  const float* W1[3];     // layer-1 fp32 weights
  u32* wf1;               // layer-1 frag-packed out (3 x 2048 x 16 B)
  u32* H;                 // h0
  u32* H1;                // h1 (row-0 zeroing only)
  const float* curv;
  const int* src;
  const int* dst;
  int* cnt;
  int* esrc;
};

__global__ __launch_bounds__(256,3) void k_main(MainArgs ma){
  const int bx = blockIdx.x;
  const int t = threadIdx.x;
  if (bx >= GEMM_BLKS){     // ---- side-work blocks (hide under the gemm) ----
    int sb = bx - GEMM_BLKS;
    if (sb < 3){            // pack layer-1 weight mat sb -> global
      const float* Wm = ma.W1[sb];
      #pragma unroll
      for (int it = 0; it < 8; ++it){
        int idx = it*256 + t;
        u32x4 q = pack_slot(Wm, idx);
        *(u32x4*)(ma.wf1 + (size_t)(sb*2048 + idx)*4) = q;
      }
    } else if (sb == 3){    // zero rows (pads gather these)
      if (t < 192){ ma.H[t] = 0; ma.H1[t] = 0; }
    } else {
      int i = (sb - 4)*256 + t;
      if (i < NE){
        int d = ma.dst[i];
        int p = atomicAdd(&ma.cnt[d], 1);
        if (p < SLAB) ma.esrc[d*SLAB + p] = (ma.src[i] + 1) * 192;
      }
    }
    return;
  }
  const int m  = bx / 157;
  const int gx = bx % 157;
  const float* __restrict__ A    = ma.A[m];
  const float* __restrict__ Bias = ma.Bias[m];
  u32* __restrict__ H = ma.H;
  const int lane = t & 63;
  const int rr = lane & 15, quad = lane >> 4;

  __shared__ u32 Wlds[8192];        // 32 frags x 64 lanes x 16 B, conflict-free b128
  {
    const float* Wm = ma.W[m];      // self-pack fp32 -> bf16 frags (L2-hot)
    #pragma unroll
    for (int it = 0; it < 8; ++it){
      int idx = it*256 + t;
      u32x4 q = pack_slot(Wm, idx);
      *(u32x4*)&Wlds[idx*4] = q;
    }
  }
  __syncthreads();                  // the only barrier in the kernel

  float sc = 1.f;
  if (m == 1) sc = sqrtf(*ma.curv);

  const int nw = 157*4;
  for (int g = gx*4 + (t >> 6); g < 3125; g += nw){
    const float* ap = A + (size_t)(g*16 + rr)*DD + quad*8;
    float4 c[8];
    #pragma unroll
    for (int ks = 0; ks < 4; ++ks){
      c[2*ks]   = *(const float4*)(ap + ks*32);
      c[2*ks+1] = *(const float4*)(ap + ks*32 + 4);
    }
    if (m != 0){
      float p = 0.f;
      #pragma unroll
      for (int i = 0; i < 8; ++i)
        p += c[i].x*c[i].x + c[i].y*c[i].y + c[i].z*c[i].z + c[i].w*c[i].w;
      p += __shfl_xor(p, 16, 64);
      p += __shfl_xor(p, 32, 64);
      float nrm = sqrtf(p);
      float sca;
      if (m == 1){    // log-map at origin: (2/sc)*artanh(sc*|y|)/|y|
        float x = sc * nrm;
        sca = (nrm > 1e-30f) ? (logf((1.f + x)/(1.f - x)) / (sc * nrm)) : 2.f;
      } else {        // l2norm
        sca = 1.f / fmaxf(nrm, 1e-12f);
      }
      #pragma unroll
      for (int i = 0; i < 8; ++i){ c[i].x*=sca; c[i].y*=sca; c[i].z*=sca; c[i].w*=sca; }
    }
    f32x4 acc[8];
    #pragma unroll
    for (int ct = 0; ct < 8; ++ct){ f32x4 z = {0.f,0.f,0.f,0.f}; acc[ct] = z; }
    #pragma unroll
    for (int ks = 0; ks < 4; ++ks){
      u32x4 bq;
      bq.x = f2bf2(c[2*ks].x,   c[2*ks].y);
      bq.y = f2bf2(c[2*ks].z,   c[2*ks].w);
      bq.z = f2bf2(c[2*ks+1].x, c[2*ks+1].y);
      bq.w = f2bf2(c[2*ks+1].z, c[2*ks+1].w);
      short8 bf = __builtin_bit_cast(short8, bq);
      #pragma unroll
      for (int ct = 0; ct < 8; ++ct){
        short8 wf = *(const short8*)&Wlds[((ct*4 + ks)*64 + lane)*4];
        acc[ct] = __builtin_amdgcn_mfma_f32_16x16x32_bf16(wf, bf, acc[ct], 0, 0, 0);
      }
    }
    #pragma unroll
    for (int ct = 0; ct < 8; ++ct){
      float4 bv = *(const float4*)(Bias + ct*16 + quad*4);
      acc[ct].x += bv.x; acc[ct].y += bv.y; acc[ct].z += bv.z; acc[ct].w += bv.w;
    }
    if (m == 2){
      float p = 0.f;
      #pragma unroll
      for (int ct = 0; ct < 8; ++ct)
        p += acc[ct].x*acc[ct].x + acc[ct].y*acc[ct].y + acc[ct].z*acc[ct].z + acc[ct].w*acc[ct].w;
      p += __shfl_xor(p, 16, 64);
      p += __shfl_xor(p, 32, 64);
      float inv = 1.f / fmaxf(sqrtf(p), 1e-12f);
      #pragma unroll
      for (int ct = 0; ct < 8; ++ct){ acc[ct].x*=inv; acc[ct].y*=inv; acc[ct].z*=inv; acc[ct].w*=inv; }
    }
    u32* hp = H + (size_t)(g*16 + rr + 1)*192 + m*64 + quad*2;
    #pragma unroll
    for (int ct = 0; ct < 8; ++ct){
      uint2 pk;
      pk.x = f2bf2(acc[ct].x, acc[ct].y);
      pk.y = f2bf2(acc[ct].z, acc[ct].w);
      *(uint2*)(hp + ct*8) = pk;
    }
  }
}

// ------------- fused agg(layer0) + gemm(layer1): H0 --gather--> H1 ---------------
// Identities: log_map(0, exp_map(0, v)) = v and l2norm(l2norm(x)) = l2norm(x), so
// aggregated means feed layer-1's matmul directly: m0 leakyrelu, m1 nothing,
// m2 one l2norm. Block = 4 waves = 16 nodes (NN = 3125*16). Phase 1: each wave
// aggregates 4 nodes; fp32 aggregates to LDS. Phase 2: waves 0-2 run the
// 16x128x128 GEMM for manifold w (B-frags from LDS, W-frags from L2), write H1.
struct FusedArgs {
  const u32* H0;
  u32* H1;
  const int* cnt;
  const int* esrc;
  const u32* Wf;          // layer-1 frag-packed weights (3 mats at +m*2048*4)
  const float* Bias[3];   // layer-1 biases
};

#define NSTR 388            // node stride in dwords (384 + 4 pad -> 2-way banks max)

__global__ __launch_bounds__(256,4) void k_fused(FusedArgs fa){
  const int t = threadIdx.x;
  const int w = t >> 6;
  const int lane = t & 63;
  const int half = lane >> 5, hl = lane & 31;
  const int rr = lane & 15, quad = lane >> 4;
  const int nbase = blockIdx.x * 16;

  __shared__ float S[16*NSTR];     // [node][m0:128 | m1:128 | m2:128 | pad4]

  // ---- phase 1: aggregate 4 nodes per wave ----
  for (int i = 0; i < 4; ++i){
    const int nb = w*4 + i;
    const int node = nbase + nb;
    const int deg = fa.cnt[node];
    const int e0 = node*SLAB;
    const int e1 = e0 + ((deg + 1) & ~1);
    const int* __restrict__ esrc = fa.esrc;
    const u32* __restrict__ Hf = fa.H0 + hl*2;

    f32x2 z2 = {0.f, 0.f};
    f32x2 a0[2] = {z2, z2};
    f32x2 a1[2] = {z2, z2};
    f32x2 a2[2] = {z2, z2};

    for (int base = e0; base < e1; base += 64){
      int nn = e1 - base; if (nn > 64) nn = 64;     // always even
      int sv = esrc[base + lane];                    // in-slab, zero-padded
      int np = nn >> 1;
      int p = 0;
      for (; p + 4 <= np; p += 4){
        uint2 q[4][3];
        #pragma unroll
        for (int u = 0; u < 4; ++u){
          int soff = __shfl(sv, 2*(p + u) + half, 64);
          const u32* hp = Hf + soff;
          q[u][0] = *(const uint2*)hp;
          q[u][1] = *(const uint2*)(hp + 64);
          q[u][2] = *(const uint2*)(hp + 128);
        }
        #pragma unroll
        for (int u = 0; u < 4; ++u){
          a0[0] += up2(q[u][0].x); a0[1] += up2(q[u][0].y);
          a1[0] += up2(q[u][1].x); a1[1] += up2(q[u][1].y);
          a2[0] += up2(q[u][2].x); a2[1] += up2(q[u][2].y);
        }
      }
      for (; p < np; ++p){
        int soff = __shfl(sv, 2*p + half, 64);
        const u32* hp = Hf + soff;
        uint2 q0 = *(const uint2*)hp;
        uint2 q1 = *(const uint2*)(hp + 64);
        uint2 q2 = *(const uint2*)(hp + 128);
        a0[0] += up2(q0.x); a0[1] += up2(q0.y);
        a1[0] += up2(q1.x); a1[1] += up2(q1.y);
        a2[0] += up2(q2.x); a2[1] += up2(q2.y);
      }
    }

    #pragma unroll
    for (int j = 0; j < 2; ++j){
      a0[j].x += __shfl_xor(a0[j].x, 32, 64); a0[j].y += __shfl_xor(a0[j].y, 32, 64);
      a1[j].x += __shfl_xor(a1[j].x, 32, 64); a1[j].y += __shfl_xor(a1[j].y, 32, 64);
      a2[j].x += __shfl_xor(a2[j].x, 32, 64); a2[j].y += __shfl_xor(a2[j].y, 32, 64);
    }
    float inv = 1.f / (float)max(deg, 1);
    #pragma unroll
    for (int j = 0; j < 2; ++j){ a0[j] *= inv; a1[j] *= inv; a2[j] *= inv; }

    // m2: single l2norm (idempotent; layer-1 pre-transform folded)
    float p2 = a2[0].x*a2[0].x + a2[0].y*a2[0].y + a2[1].x*a2[1].x + a2[1].y*a2[1].y;
    #pragma unroll
    for (int off = 1; off < 32; off <<= 1) p2 += __shfl_xor(p2, off, 64);
    float s2 = 1.f / fmaxf(sqrtf(p2), 1e-12f);

    float* sp = &S[nb*NSTR];
    if (half == 0){
      f32x4 v0 = { a0[0].x > 0.f ? a0[0].x : 0.2f*a0[0].x,
                   a0[0].y > 0.f ? a0[0].y : 0.2f*a0[0].y,
                   a0[1].x > 0.f ? a0[1].x : 0.2f*a0[1].x,
                   a0[1].y > 0.f ? a0[1].y : 0.2f*a0[1].y };
      *(f32x4*)(sp + hl*4) = v0;
      f32x4 v1 = { a1[0].x, a1[0].y, a1[1].x, a1[1].y };   // identity (log∘exp)
      *(f32x4*)(sp + 128 + hl*4) = v1;
    } else {
      f32x4 v2 = { a2[0].x*s2, a2[0].y*s2, a2[1].x*s2, a2[1].y*s2 };
      *(f32x4*)(sp + 256 + hl*4) = v2;
    }
  }
  __syncthreads();

  // ---- phase 2: wave w < 3 computes manifold w's 16x128 output tile ----
  if (w < 3){
    const int m = w;
    short8 bf[4];
    const float* sp = &S[rr*NSTR + m*128];
    #pragma unroll
    for (int ks = 0; ks < 4; ++ks){
      f32x4 lo = *(const f32x4*)(sp + ks*32 + quad*8);
      f32x4 hi = *(const f32x4*)(sp + ks*32 + quad*8 + 4);
      u32x4 bq;
      bq.x = f2bf2(lo.x, lo.y); bq.y = f2bf2(lo.z, lo.w);
      bq.z = f2bf2(hi.x, hi.y); bq.w = f2bf2(hi.z, hi.w);
      bf[ks] = __builtin_bit_cast(short8, bq);
    }
    const u32* __restrict__ wbase = fa.Wf + (size_t)m*8192;
    const float* __restrict__ Bias = fa.Bias[m];
    f32x4 acc[8];
    #pragma unroll
    for (int ct = 0; ct < 8; ++ct){ f32x4 z = {0.f,0.f,0.f,0.f}; acc[ct] = z; }
    #pragma unroll
    for (int ct = 0; ct < 8; ++ct){
      short8 wfr[4];
      #pragma unroll
      for (int ks = 0; ks < 4; ++ks)
        wfr[ks] = *(const short8*)(wbase + ((ct*4 + ks)*64 + lane)*4);
      #pragma unroll
      for (int ks = 0; ks < 4; ++ks)
        acc[ct] = __builtin_amdgcn_mfma_f32_16x16x32_bf16(wfr[ks], bf[ks], acc[ct], 0, 0, 0);
    }
    #pragma unroll
    for (int ct = 0; ct < 8; ++ct){
      float4 bv = *(const float4*)(Bias + ct*16 + quad*4);
      acc[ct].x += bv.x; acc[ct].y += bv.y; acc[ct].z += bv.z; acc[ct].w += bv.w;
    }
    if (m == 2){
      float p = 0.f;
      #pragma unroll
      for (int ct = 0; ct < 8; ++ct)
        p += acc[ct].x*acc[ct].x + acc[ct].y*acc[ct].y + acc[ct].z*acc[ct].z + acc[ct].w*acc[ct].w;
      p += __shfl_xor(p, 16, 64);
      p += __shfl_xor(p, 32, 64);
      float nv = 1.f / fmaxf(sqrtf(p), 1e-12f);
      #pragma unroll
      for (int ct = 0; ct < 8; ++ct){ acc[ct].x*=nv; acc[ct].y*=nv; acc[ct].z*=nv; acc[ct].w*=nv; }
    }
    u32* hp = fa.H1 + (size_t)(nbase + rr + 1)*192 + m*64 + quad*2;
    #pragma unroll
    for (int ct = 0; ct < 8; ++ct){
      uint2 pk;
      pk.x = f2bf2(acc[ct].x, acc[ct].y);
      pk.y = f2bf2(acc[ct].z, acc[ct].w);
      *(uint2*)(hp + ct*8) = pk;
    }
  }
}

// ------- final mean-aggregate + post-transform (layer 1) -------------------------
struct AggArgs {
  const u32* H;
  float* O;
  const int* cnt;
  const int* esrc;
  const float* curv;
};

__global__ __launch_bounds__(256) void k_agg(AggArgs aa){
  const int tid = threadIdx.x;
  const int lane = tid & 63;
  const int half = lane >> 5, hl = lane & 31;
  const int node = blockIdx.x*4 + (tid >> 6);
  if (node >= NN) return;
  const int deg = aa.cnt[node];
  const int e0 = node*SLAB;
  const int e1 = e0 + ((deg + 1) & ~1);
  const int* __restrict__ esrc = aa.esrc;
  const u32* __restrict__ Hf = aa.H + hl*2;

  f32x2 z2 = {0.f, 0.f};
  f32x2 a0[2] = {z2, z2};
  f32x2 a1[2] = {z2, z2};
  f32x2 a2[2] = {z2, z2};

  for (int base = e0; base < e1; base += 64){
    int nn = e1 - base; if (nn > 64) nn = 64;
    int sv = esrc[base + lane];                    // in-slab, zero-padded
    int np = nn >> 1;
    int p = 0;
    for (; p + 4 <= np; p += 4){
      uint2 q[4][3];
      #pragma unroll
      for (int u = 0; u < 4; ++u){
        int soff = __shfl(sv, 2*(p + u) + half, 64);
        const u32* hp = Hf + soff;
        q[u][0] = *(const uint2*)hp;
        q[u][1] = *(const uint2*)(hp + 64);
        q[u][2] = *(const uint2*)(hp + 128);
      }
      #pragma unroll
      for (int u = 0; u < 4; ++u){
        a0[0] += up2(q[u][0].x); a0[1] += up2(q[u][0].y);
        a1[0] += up2(q[u][1].x); a1[1] += up2(q[u][1].y);
        a2[0] += up2(q[u][2].x); a2[1] += up2(q[u][2].y);
      }
    }
    for (; p < np; ++p){
      int soff = __shfl(sv, 2*p + half, 64);
      const u32* hp = Hf + soff;
      uint2 q0 = *(const uint2*)hp;
      uint2 q1 = *(const uint2*)(hp + 64);
      uint2 q2 = *(const uint2*)(hp + 128);
      a0[0] += up2(q0.x); a0[1] += up2(q0.y);
      a1[0] += up2(q1.x); a1[1] += up2(q1.y);
      a2[0] += up2(q2.x); a2[1] += up2(q2.y);
    }
  }

  #pragma unroll
  for (int j = 0; j < 2; ++j){
    a0[j].x += __shfl_xor(a0[j].x, 32, 64); a0[j].y += __shfl_xor(a0[j].y, 32, 64);
    a1[j].x += __shfl_xor(a1[j].x, 32, 64); a1[j].y += __shfl_xor(a1[j].y, 32, 64);
    a2[j].x += __shfl_xor(a2[j].x, 32, 64); a2[j].y += __shfl_xor(a2[j].y, 32, 64);
  }
  float inv = 1.f / (float)max(deg, 1);
  #pragma unroll
  for (int j = 0; j < 2; ++j){ a0[j] *= inv; a1[j] *= inv; a2[j] *= inv; }

  float p1 = a1[0].x*a1[0].x + a1[0].y*a1[0].y + a1[1].x*a1[1].x + a1[1].y*a1[1].y;
  float p2 = a2[0].x*a2[0].x + a2[0].y*a2[0].y + a2[1].x*a2[1].x + a2[1].y*a2[1].y;
  #pragma unroll
  for (int off = 1; off < 32; off <<= 1){
    p1 += __shfl_xor(p1, off, 64);
    p2 += __shfl_xor(p2, off, 64);
  }
  float n1 = sqrtf(p1);
  float scv = sqrtf(*aa.curv);
  float x = scv * n1;
  float s1 = (n1 > 1e-30f) ? (tanhf(0.5f*x) / x) : 0.5f;   // exp-map at origin
  float s2 = 1.f / fmaxf(sqrtf(p2), 1e-12f);               // l2norm

  float* op = aa.O + (size_t)node*384;
  if (half == 0){
    float4 e4 = make_float4(a0[0].x > 0.f ? a0[0].x : 0.2f*a0[0].x,
                            a0[0].y > 0.f ? a0[0].y : 0.2f*a0[0].y,
                            a0[1].x > 0.f ? a0[1].x : 0.2f*a0[1].x,
                            a0[1].y > 0.f ? a0[1].y : 0.2f*a0[1].y);
    *(float4*)(op + hl*4) = e4;
    *(float4*)(op + 128 + hl*4) = make_float4(a1[0].x*s1, a1[0].y*s1, a1[1].x*s1, a1[1].y*s1);
  } else {
    *(float4*)(op + 256 + hl*4) = make_float4(a2[0].x*s2, a2[0].y*s2, a2[1].x*s2, a2[1].y*s2);
  }
}

extern "C" void kernel_launch(void* const* d_in, const int* in_sizes, int n_in,
                              void* d_out, int out_size, void* d_ws, size_t ws_size,
                              hipStream_t stream){
  (void)in_sizes; (void)n_in; (void)out_size; (void)ws_size;
  const int*   src    = (const int*)  d_in[0];
  const int*   dst    = (const int*)  d_in[1];
  const float* e_emb  = (const float*)d_in[2];
  const float* b_emb  = (const float*)d_in[3];
  const float* s_emb  = (const float*)d_in[4];
  const float* e_W    = (const float*)d_in[5];
  const float* e_b    = (const float*)d_in[6];
  const float* b_W    = (const float*)d_in[7];
  const float* b_b    = (const float*)d_in[8];
  const float* s_W    = (const float*)d_in[9];
  const float* s_b    = (const float*)d_in[10];
  const float* b_curv = (const float*)d_in[11];
  float* out = (float*)d_out;

  char* ws = (char*)d_ws;
  size_t off = 0;
  auto alloc = [&](size_t bytes) -> void* {
    void* p = (void*)(ws + off);
    off += (bytes + 255) & ~(size_t)255;
    return p;
  };
  int* cnt  = (int*)alloc((size_t)NN*4);              // \ contiguous: one memset
  int* esrc = (int*)alloc((size_t)NN*SLAB*4);         // /  covers both
  size_t zbytes = off;                                // cnt + esrc (+ padding)
  u32* h0   = (u32*)alloc((size_t)(NN+1)*192*4);      // row 0 zeroed in k_main
  u32* h1   = (u32*)alloc((size_t)(NN+1)*192*4);      // row 0 zeroed in k_main
  u32* wf1  = (u32*)alloc((size_t)3*2048*16);         // layer-1 frag-packed bf16 W

  (void)hipMemsetAsync(ws, 0, zbytes, stream);        // cnt + esrc in one shot

  // ----- layer-0 GEMM || {layer-1 W pack, zero rows, 1-pass CSR build} -----
  MainArgs m;
  m.A[0]=e_emb; m.A[1]=b_emb; m.A[2]=s_emb;
  m.Bias[0]=e_b; m.Bias[1]=b_b; m.Bias[2]=s_b;
  m.W[0]=e_W;  m.W[1]=b_W;  m.W[2]=s_W;
  m.W1[0]=e_W+16384; m.W1[1]=b_W+16384; m.W1[2]=s_W+16384;
  m.wf1 = wf1; m.H = h0; m.H1 = h1; m.curv = b_curv;
  m.src = src; m.dst = dst; m.cnt = cnt; m.esrc = esrc;
  k_main<<<GEMM_BLKS + 4 + (NE+255)/256, 256, 0, stream>>>(m);

  // ----- fused: agg(layer0) + gemm(layer1): h0 -> h1 -----
  FusedArgs f;
  f.H0 = h0; f.H1 = h1; f.cnt = cnt; f.esrc = esrc;
  f.Wf = wf1;
  f.Bias[0] = e_b + DD; f.Bias[1] = b_b + DD; f.Bias[2] = s_b + DD;
  k_fused<<<NN/16, 256, 0, stream>>>(f);

  // ----- layer-1 aggregate + final transforms: h1 -> out -----
  AggArgs a;
  a.H = h1; a.O = out; a.cnt = cnt; a.esrc = esrc; a.curv = b_curv;
  k_agg<<<(NN + 3)/4, 256, 0, stream>>>(a);
}